// Round 5
// baseline (235.369 us; speedup 1.0000x reference)
//
#include <hip/hip_runtime.h>
#include <math.h>

#define NN 10000
#define NE 160000
#define NRBF 50
#define WNUM 2304
#define EPSV 1e-5f

#define A_P1 0.125f
#define A_P2 0.17677669529663687f
#define A_P3 0.125f
#define A_P4 0.17677669529663687f
#define INV_SQRT3 0.5773502691896258f
#define INV_SQRT_M0 0.17677669529663687f
#define INV_SQRT_M1 0.25f

typedef __attribute__((ext_vector_type(8))) short bf16x8;
typedef __attribute__((ext_vector_type(4))) float f32x4;
typedef __attribute__((ext_vector_type(4))) int i32x4;

#define MFMA16(a, b, c) __builtin_amdgcn_mfma_f32_16x16x32_bf16(a, b, c, 0, 0, 0)

__device__ __forceinline__ short f2bf(float x) {
  unsigned u = __float_as_uint(x);
  unsigned r = (u + 0x7fffu + ((u >> 16) & 1u)) >> 16;
  return (short)r;
}

// ---- weight prep: transpose + bf16 + fragment-order packing ----
// Per 16-col tile t: 1024 shorts = [chunk(2)][lane(64)][kk(8)].
// Lane l, chunk c holds B[row = t*16 + (l&15)][k = (l>>4)*8 + c*32 + kk].
__global__ void prep_weights(const float* __restrict__ W1, const float* __restrict__ W2,
                             const float* __restrict__ W3, short* __restrict__ W1P,
                             short* __restrict__ W2P, short* __restrict__ W3P) {
  int s = blockIdx.x * 256 + threadIdx.x;
  if (s < WNUM * 64) {
    int t = s >> 10, r = s & 1023;
    int ch = r >> 9, l = (r >> 3) & 63, kk = r & 7;
    int row = t * 16 + (l & 15);
    int k = ((l >> 4) << 3) + (ch << 5) + kk;
    W3P[s] = f2bf(W3[k * WNUM + row]);
  } else if (s < WNUM * 64 + 4096) {
    int s2 = s - WNUM * 64;
    int t = s2 >> 10, r = s2 & 1023;
    int ch = r >> 9, l = (r >> 3) & 63, kk = r & 7;
    int row = t * 16 + (l & 15);
    int k = ((l >> 4) << 3) + (ch << 5) + kk;
    W1P[s2] = f2bf(k < NRBF ? W1[k * 64 + row] : 0.f);
  } else if (s < WNUM * 64 + 8192) {
    int s2 = s - WNUM * 64 - 4096;
    int t = s2 >> 10, r = s2 & 1023;
    int ch = r >> 9, l = (r >> 3) & 63, kk = r & 7;
    int row = t * 16 + (l & 15);
    int k = ((l >> 4) << 3) + (ch << 5) + kk;
    W2P[s2] = f2bf(W2[k * 64 + row]);
  }
}

// One 16-col tile T for ALL 4 edge-groups: 2 B loads, 8 MFMA, custom fold.
// Fold body sees: g (group), v (f32x4 tile values for group's 4 edge rows).
#define TILE4(T, ...)                                               \
  {                                                                 \
    const short* _wb = W3P + ((T) << 10) + (l << 3);                \
    bf16x8 _B0 = *(const bf16x8*)_wb;                               \
    bf16x8 _B1 = *(const bf16x8*)(_wb + 512);                       \
    float _bias = b3[((T) << 4) + lr];                              \
    _Pragma("unroll")                                               \
    for (int g = 0; g < 4; ++g) {                                   \
      f32x4 _d = {_bias, _bias, _bias, _bias};                      \
      _d = MFMA16(a0g[g], _B0, _d);                                 \
      f32x4 v = MFMA16(a1g[g], _B1, _d);                            \
      __VA_ARGS__                                                   \
    }                                                               \
  }

__global__ __launch_bounds__(256, 3) void edge_kernel(
    const float* __restrict__ h, const int* __restrict__ eidx,
    const float* __restrict__ esh, const float* __restrict__ ef,
    const short* __restrict__ W1P, const float* __restrict__ b1,
    const short* __restrict__ W2P, const float* __restrict__ b2,
    const short* __restrict__ W3P, const float* __restrict__ b3,
    float* __restrict__ agg, float* __restrict__ cnt) {
  __shared__ short buf0[64 * 72];  // efs -> h2s
  __shared__ short h1s[64 * 72];
  // coef (24 KB): s0c[0..2047]=A_P3*s0[u], s1p[2048..5119]=A_P2*s1[u][i],
  // d4s[5120..6143]=A_P4*inv_sqrt3*(s1.y1). Reused as reduce scratch after fold.
  __shared__ float coef[6144];
  __shared__ float y0s[64], y1s[192];
  __shared__ float b1s[64], b2s[64];
  __shared__ int dsts[64];

  const int tid = threadIdx.x;
  const int e0 = blockIdx.x * 64;

  // ---- Phase A: staging ----
  for (int idx = tid; idx < 64 * 64; idx += 256) {
    int e = idx >> 6, k = idx & 63;
    float v = (k < NRBF) ? ef[(long)(e0 + e) * NRBF + k] : 0.f;
    buf0[e * 72 + k] = f2bf(v);
  }
  if (tid < 64) { b1s[tid] = b1[tid]; b2s[tid] = b2[tid]; }
  {
    int e = tid >> 2, q = tid & 3;
    int ge = e0 + e;
    int src = eidx[ge];
    float y0 = esh[ge * 4 + 0];
    float y1x = esh[ge * 4 + 1], y1y = esh[ge * 4 + 2], y1z = esh[ge * 4 + 3];
    const float* hs = h + (long)src * 80;
    for (int u = q; u < 32; u += 4) coef[u * 64 + e] = A_P3 * hs[u];
    for (int u = q; u < 16; u += 4) {
      float sx = hs[32 + u * 3], sy = hs[33 + u * 3], sz = hs[34 + u * 3];
      coef[2048 + (0 * 16 + u) * 64 + e] = A_P2 * sx;
      coef[2048 + (1 * 16 + u) * 64 + e] = A_P2 * sy;
      coef[2048 + (2 * 16 + u) * 64 + e] = A_P2 * sz;
      coef[5120 + u * 64 + e] = A_P4 * INV_SQRT3 * (sx * y1x + sy * y1y + sz * y1z);
    }
    if (q == 0) {
      y0s[e] = y0;
      y1s[e] = y1x; y1s[64 + e] = y1y; y1s[128 + e] = y1z;
      dsts[e] = eidx[NE + ge];
    }
  }
  __syncthreads();

  const int wid = tid >> 6, l = tid & 63;
  const int lr = l & 15, lg = l >> 4;
  const int g16 = lg * 4;  // sub-row base within a group

  // ---- MLP layer 1 ----
  {
    const int er = wid * 16;
    bf16x8 a0 = *(const bf16x8*)&buf0[(er + lr) * 72 + lg * 8];
    bf16x8 a1 = *(const bf16x8*)&buf0[(er + lr) * 72 + 32 + lg * 8];
#pragma unroll
    for (int jt = 0; jt < 4; ++jt) {
      const short* wb = W1P + (jt << 10) + (l << 3);
      bf16x8 b0 = *(const bf16x8*)wb;
      bf16x8 b1f = *(const bf16x8*)(wb + 512);
      float bias = b1s[jt * 16 + lr];
      f32x4 d = {bias, bias, bias, bias};
      d = MFMA16(a0, b0, d);
      d = MFMA16(a1, b1f, d);
#pragma unroll
      for (int r = 0; r < 4; ++r) {
        float x = d[r];
        x = x / (1.f + __expf(-x));
        h1s[(er + lg * 4 + r) * 72 + jt * 16 + lr] = f2bf(x);
      }
    }
  }
  __syncthreads();

  // ---- MLP layer 2 (h2 -> buf0) ----
  {
    const int er = wid * 16;
    bf16x8 a0 = *(const bf16x8*)&h1s[(er + lr) * 72 + lg * 8];
    bf16x8 a1 = *(const bf16x8*)&h1s[(er + lr) * 72 + 32 + lg * 8];
#pragma unroll
    for (int jt = 0; jt < 4; ++jt) {
      const short* wb = W2P + (jt << 10) + (l << 3);
      bf16x8 b0 = *(const bf16x8*)wb;
      bf16x8 b1f = *(const bf16x8*)(wb + 512);
      float bias = b2s[jt * 16 + lr];
      f32x4 d = {bias, bias, bias, bias};
      d = MFMA16(a0, b0, d);
      d = MFMA16(a1, b1f, d);
#pragma unroll
      for (int r = 0; r < 4; ++r) {
        float x = d[r];
        x = x / (1.f + __expf(-x));
        buf0[(er + lg * 4 + r) * 72 + jt * 16 + lr] = f2bf(x);
      }
    }
  }
  __syncthreads();

  // ---- Phase C: wave = quarter of tiles, ALL 4 edge groups ----
  bf16x8 a0g[4], a1g[4];
#pragma unroll
  for (int g = 0; g < 4; ++g) {
    a0g[g] = *(const bf16x8*)&buf0[(g * 16 + lr) * 72 + lg * 8];
    a1g[g] = *(const bf16x8*)&buf0[(g * 16 + lr) * 72 + 32 + lg * 8];
  }

  f32x4 s0[4], s1[4], mx[4], my[4], mz[4];
#pragma unroll
  for (int g = 0; g < 4; ++g) {
    s0[g] = (f32x4){0, 0, 0, 0}; s1[g] = (f32x4){0, 0, 0, 0};
    mx[g] = (f32x4){0, 0, 0, 0}; my[g] = (f32x4){0, 0, 0, 0};
    mz[g] = (f32x4){0, 0, 0, 0};
  }

  if (wid == 0) {
    // w1 pairs 0..17 (tiles 0..35)
#pragma unroll 1
    for (int p = 0; p < 18; ++p) {
      TILE4(2 * p, {
        f32x4 c = *(const f32x4*)&coef[p * 64 + g * 16 + g16];
        _Pragma("unroll") for (int r = 0; r < 4; ++r) s0[g][r] += c[r] * v[r];
      });
      TILE4(2 * p + 1, {
        f32x4 c = *(const f32x4*)&coef[p * 64 + g * 16 + g16];
        _Pragma("unroll") for (int r = 0; r < 4; ++r) s1[g][r] += c[r] * v[r];
      });
    }
#pragma unroll
    for (int g = 0; g < 4; ++g) {
      f32x4 y0v = *(const f32x4*)&y0s[g * 16 + g16];
#pragma unroll
      for (int r = 0; r < 4; ++r) { s0[g][r] *= y0v[r]; s1[g][r] *= y0v[r]; }
    }
  } else if (wid == 1) {
    // w1 pairs 18..31 (tiles 36..63)
#pragma unroll 1
    for (int p = 18; p < 32; ++p) {
      TILE4(2 * p, {
        f32x4 c = *(const f32x4*)&coef[p * 64 + g * 16 + g16];
        _Pragma("unroll") for (int r = 0; r < 4; ++r) s0[g][r] += c[r] * v[r];
      });
      TILE4(2 * p + 1, {
        f32x4 c = *(const f32x4*)&coef[p * 64 + g * 16 + g16];
        _Pragma("unroll") for (int r = 0; r < 4; ++r) s1[g][r] += c[r] * v[r];
      });
    }
    // w2 u 0..7 (tiles 64..71)
#pragma unroll 2
    for (int u = 0; u < 8; ++u) {
      TILE4(64 + u, {
        f32x4 cx = *(const f32x4*)&coef[2048 + (0 * 16 + u) * 64 + g * 16 + g16];
        f32x4 cy = *(const f32x4*)&coef[2048 + (1 * 16 + u) * 64 + g * 16 + g16];
        f32x4 cz = *(const f32x4*)&coef[2048 + (2 * 16 + u) * 64 + g * 16 + g16];
        _Pragma("unroll") for (int r = 0; r < 4; ++r) {
          mx[g][r] += cx[r] * v[r];
          my[g][r] += cy[r] * v[r];
          mz[g][r] += cz[r] * v[r];
        }
      });
    }
#pragma unroll
    for (int g = 0; g < 4; ++g) {
      f32x4 y0v = *(const f32x4*)&y0s[g * 16 + g16];
#pragma unroll
      for (int r = 0; r < 4; ++r) {
        s0[g][r] *= y0v[r]; s1[g][r] *= y0v[r];
        mx[g][r] *= y0v[r]; my[g][r] *= y0v[r]; mz[g][r] *= y0v[r];
      }
    }
  } else if (wid == 2) {
    // w2 u 8..15 (tiles 72..79)
#pragma unroll 2
    for (int u = 8; u < 16; ++u) {
      TILE4(64 + u, {
        f32x4 cx = *(const f32x4*)&coef[2048 + (0 * 16 + u) * 64 + g * 16 + g16];
        f32x4 cy = *(const f32x4*)&coef[2048 + (1 * 16 + u) * 64 + g * 16 + g16];
        f32x4 cz = *(const f32x4*)&coef[2048 + (2 * 16 + u) * 64 + g * 16 + g16];
        _Pragma("unroll") for (int r = 0; r < 4; ++r) {
          mx[g][r] += cx[r] * v[r];
          my[g][r] += cy[r] * v[r];
          mz[g][r] += cz[r] * v[r];
        }
      });
    }
#pragma unroll
    for (int g = 0; g < 4; ++g) {
      f32x4 y0v = *(const f32x4*)&y0s[g * 16 + g16];
#pragma unroll
      for (int r = 0; r < 4; ++r) {
        mx[g][r] *= y0v[r]; my[g][r] *= y0v[r]; mz[g][r] *= y0v[r];
      }
    }
    // w3 u 0..27 (tiles 80..107): t3 accumulates in s0 slot
#pragma unroll 2
    for (int u = 0; u < 28; ++u) {
      TILE4(80 + u, {
        f32x4 c = *(const f32x4*)&coef[u * 64 + g * 16 + g16];
        _Pragma("unroll") for (int r = 0; r < 4; ++r) s0[g][r] += c[r] * v[r];
      });
    }
#pragma unroll
    for (int g = 0; g < 4; ++g) {
      f32x4 yx = *(const f32x4*)&y1s[g * 16 + g16];
      f32x4 yy = *(const f32x4*)&y1s[64 + g * 16 + g16];
      f32x4 yz = *(const f32x4*)&y1s[128 + g * 16 + g16];
#pragma unroll
      for (int r = 0; r < 4; ++r) {
        mx[g][r] += yx[r] * s0[g][r];
        my[g][r] += yy[r] * s0[g][r];
        mz[g][r] += yz[r] * s0[g][r];
      }
      s0[g] = (f32x4){0, 0, 0, 0};
    }
  } else {
    // w3 u 28..31 (tiles 108..111): immediate fold with y1
    {
      f32x4 yx[4], yy[4], yz[4];
#pragma unroll
      for (int g = 0; g < 4; ++g) {
        yx[g] = *(const f32x4*)&y1s[g * 16 + g16];
        yy[g] = *(const f32x4*)&y1s[64 + g * 16 + g16];
        yz[g] = *(const f32x4*)&y1s[128 + g * 16 + g16];
      }
#pragma unroll 2
      for (int u = 28; u < 32; ++u) {
        TILE4(80 + u, {
          f32x4 c = *(const f32x4*)&coef[u * 64 + g * 16 + g16];
          _Pragma("unroll") for (int r = 0; r < 4; ++r) {
            float t = c[r] * v[r];
            mx[g][r] += yx[g][r] * t;
            my[g][r] += yy[g][r] * t;
            mz[g][r] += yz[g][r] * t;
          }
        });
      }
    }
    // w4 pairs u 0..15 (tiles 112..143), no y0 scaling
#pragma unroll 1
    for (int p = 0; p < 16; ++p) {
      TILE4(112 + 2 * p, {
        f32x4 c = *(const f32x4*)&coef[5120 + p * 64 + g * 16 + g16];
        _Pragma("unroll") for (int r = 0; r < 4; ++r) s0[g][r] += c[r] * v[r];
      });
      TILE4(113 + 2 * p, {
        f32x4 c = *(const f32x4*)&coef[5120 + p * 64 + g * 16 + g16];
        _Pragma("unroll") for (int r = 0; r < 4; ++r) s1[g][r] += c[r] * v[r];
      });
    }
  }

  if (tid < 64) atomicAdd(cnt + dsts[tid], 1.0f);

  // ---- cross-wave reduce tree over dead coef LDS (stride 24 floats) ----
  // STORE_G/ADD_G: one group's 5 f32x4 at base + l*24
#define STORE_G(G, BASE)                                \
  {                                                     \
    float* p = coef + (BASE) + l * 24;                  \
    *(f32x4*)(p + 0) = s0[G];  *(f32x4*)(p + 4) = s1[G];\
    *(f32x4*)(p + 8) = mx[G];  *(f32x4*)(p + 12) = my[G];\
    *(f32x4*)(p + 16) = mz[G];                          \
  }
#define ADD_G(G, BASE)                                                   \
  {                                                                      \
    const float* p = coef + (BASE) + l * 24;                             \
    f32x4 t0 = *(const f32x4*)(p + 0), t1 = *(const f32x4*)(p + 4);      \
    f32x4 t2 = *(const f32x4*)(p + 8), t3_ = *(const f32x4*)(p + 12);    \
    f32x4 t4 = *(const f32x4*)(p + 16);                                  \
    _Pragma("unroll") for (int r = 0; r < 4; ++r) {                      \
      s0[G][r] += t0[r]; s1[G][r] += t1[r]; mx[G][r] += t2[r];           \
      my[G][r] += t3_[r]; mz[G][r] += t4[r];                             \
    }                                                                    \
  }

  __syncthreads();                       // coef fold-reads done everywhere
  if (wid == 1) { STORE_G(0, 0); STORE_G(1, 1536); }
  if (wid == 3) { STORE_G(0, 3072); STORE_G(1, 4608); }
  __syncthreads();
  if (wid == 0) { ADD_G(0, 0); ADD_G(1, 1536); }
  if (wid == 2) { ADD_G(0, 3072); ADD_G(1, 4608); }
  __syncthreads();
  if (wid == 1) { STORE_G(2, 0); STORE_G(3, 1536); }
  if (wid == 3) { STORE_G(2, 3072); STORE_G(3, 4608); }
  __syncthreads();
  if (wid == 0) { ADD_G(2, 0); ADD_G(3, 1536); }
  if (wid == 2) { ADD_G(2, 3072); ADD_G(3, 4608); }
  __syncthreads();
  if (wid == 2) { STORE_G(0, 0); STORE_G(1, 1536); STORE_G(2, 3072); STORE_G(3, 4608); }
  __syncthreads();
  if (wid == 0) {
    ADD_G(0, 0); ADD_G(1, 1536); ADD_G(2, 3072); ADD_G(3, 4608);
    // ---- scatter: 5120 atomics, wave 0 only ----
#pragma unroll
    for (int g = 0; g < 4; ++g) {
      i32x4 dd = *(const i32x4*)&dsts[g * 16 + g16];
#pragma unroll
      for (int r = 0; r < 4; ++r) {
        float* base = agg + (long)dd[r] * 80;
        atomicAdd(base + lr, s0[g][r]);
        atomicAdd(base + 16 + lr, s1[g][r]);
        atomicAdd(base + 32 + lr * 3 + 0, mx[g][r]);
        atomicAdd(base + 32 + lr * 3 + 1, my[g][r]);
        atomicAdd(base + 32 + lr * 3 + 2, mz[g][r]);
      }
    }
  }
#undef STORE_G
#undef ADD_G
}

__global__ __launch_bounds__(256) void node_a(
    const float* __restrict__ h, const float* __restrict__ A0,
    const float* __restrict__ A1p, const float* __restrict__ agg,
    const float* __restrict__ cnt, float* __restrict__ outpre,
    float* __restrict__ stats) {
  __shared__ float redw[4][80];
  const int tid = threadIdx.x;
  const int wid = tid >> 6, l = tid & 63;
  const int n = blockIdx.x * 256 + tid;
  float x0[32], x1[48];
#pragma unroll
  for (int w = 0; w < 32; w++) x0[w] = 0.f;
#pragma unroll
  for (int c = 0; c < 48; c++) x1[c] = 0.f;
  if (n < NN) {
    const float* hr = h + (long)n * 80;
    const float* ar = agg + (long)n * 80;
    float inv = 1.f / fmaxf(cnt[n], 1.f);
#pragma unroll 1
    for (int u = 0; u < 32; u++) {
      float hu = hr[u];
#pragma unroll
      for (int w = 0; w < 32; w++) x0[w] += hu * A0[u * 32 + w];
    }
#pragma unroll
    for (int w = 0; w < 32; w++) x0[w] = x0[w] * INV_SQRT_M0 + ar[w] * inv;
#pragma unroll 1
    for (int u = 0; u < 16; u++) {
      float a = hr[32 + u * 3], b_ = hr[33 + u * 3], c_ = hr[34 + u * 3];
#pragma unroll
      for (int w = 0; w < 16; w++) {
        float Aw = A1p[u * 16 + w];
        x1[w * 3 + 0] += a * Aw;
        x1[w * 3 + 1] += b_ * Aw;
        x1[w * 3 + 2] += c_ * Aw;
      }
    }
#pragma unroll
    for (int c = 0; c < 48; c++) x1[c] = x1[c] * INV_SQRT_M1 + ar[32 + c] * inv;
    float* opr = outpre + (long)n * 80;
#pragma unroll
    for (int w = 0; w < 32; w++) opr[w] = x0[w];
#pragma unroll
    for (int c = 0; c < 48; c++) opr[32 + c] = x1[c];
  }
#pragma unroll 1
  for (int c = 0; c < 32; ++c) {
    float s = x0[c];
#pragma unroll
    for (int m = 32; m >= 1; m >>= 1) s += __shfl_xor(s, m, 64);
    if (l == 0) redw[wid][c] = s;
  }
#pragma unroll 1
  for (int c = 0; c < 32; ++c) {
    float v = x0[c];
    float s = v * v;
#pragma unroll
    for (int m = 32; m >= 1; m >>= 1) s += __shfl_xor(s, m, 64);
    if (l == 0) redw[wid][32 + c] = s;
  }
#pragma unroll 1
  for (int u = 0; u < 16; ++u) {
    float s = x1[u * 3] * x1[u * 3] + x1[u * 3 + 1] * x1[u * 3 + 1] +
              x1[u * 3 + 2] * x1[u * 3 + 2];
#pragma unroll
    for (int m = 32; m >= 1; m >>= 1) s += __shfl_xor(s, m, 64);
    if (l == 0) redw[wid][64 + u] = s;
  }
  __syncthreads();
  if (tid < 80)
    atomicAdd(&stats[tid],
              redw[0][tid] + redw[1][tid] + redw[2][tid] + redw[3][tid]);
}

__global__ void node_b(const float* __restrict__ outpre, const float* __restrict__ stats,
                       const float* __restrict__ bnw0, const float* __restrict__ bnb0,
                       const float* __restrict__ bnw1, const float* __restrict__ h,
                       float* __restrict__ out) {
  int idx = blockIdx.x * 256 + threadIdx.x;
  if (idx >= NN * 80) return;
  int c = idx % 80;
  float v = outpre[idx];
  const float invN = 1.f / NN;
  float o;
  if (c < 32) {
    float mu = stats[c] * invN;
    float var = stats[32 + c] * invN - mu * mu;
    o = (v - mu) * rsqrtf(var + EPSV) * bnw0[c] + bnb0[c];
  } else {
    int u = (c - 32) / 3;
    float nr = stats[64 + u] * invN;
    o = v * rsqrtf(nr + EPSV) * bnw1[u];
  }
  out[idx] = o + h[idx];
}

extern "C" void kernel_launch(void* const* d_in, const int* in_sizes, int n_in,
                              void* d_out, int out_size, void* d_ws, size_t ws_size,
                              hipStream_t stream) {
  const float* h    = (const float*)d_in[0];
  const int*   eidx = (const int*)d_in[1];
  const float* esh  = (const float*)d_in[2];
  const float* ef   = (const float*)d_in[3];
  const float* W1   = (const float*)d_in[4];
  const float* b1   = (const float*)d_in[5];
  const float* W2   = (const float*)d_in[6];
  const float* b2   = (const float*)d_in[7];
  const float* W3   = (const float*)d_in[8];
  const float* b3   = (const float*)d_in[9];
  const float* A0   = (const float*)d_in[10];
  const float* A1p  = (const float*)d_in[11];
  const float* bnw0 = (const float*)d_in[12];
  const float* bnb0 = (const float*)d_in[13];
  const float* bnw1 = (const float*)d_in[14];
  float* out = (float*)d_out;

  float* ws = (float*)d_ws;
  float* agg    = ws;             // 800000
  float* cnt    = ws + 800000;    // 10000
  float* stats  = ws + 810000;    // 80
  float* outpre = ws + 810080;    // 800000
  short* W3P    = (short*)(ws + 1610080);  // 147456 shorts
  short* W1P    = W3P + WNUM * 64;         // 4096 shorts
  short* W2P    = W1P + 4096;              // 4096 shorts

  hipMemsetAsync(agg, 0, (size_t)810080 * sizeof(float), stream);

  prep_weights<<<(WNUM * 64 + 8192 + 255) / 256, 256, 0, stream>>>(W1, W2, W3, W1P,
                                                                   W2P, W3P);
  edge_kernel<<<NE / 64, 256, 0, stream>>>(h, eidx, esh, ef, W1P, b1, W2P, b2, W3P, b3,
                                           agg, cnt);
  node_a<<<(NN + 255) / 256, 256, 0, stream>>>(h, A0, A1p, agg, cnt, outpre, stats);
  node_b<<<(NN * 80 + 255) / 256, 256, 0, stream>>>(outpre, stats, bnw0, bnb0, bnw1, h,
                                                    out);
}